// Round 10
// baseline (1839.122 us; speedup 1.0000x reference)
//
#include <hip/hip_runtime.h>
#include <math.h>

#define BB 128
#define QQ 200
#define CC 92
#define CMPAD (QQ * QQ + 80) // pad: idle lanes 50..63 read up to row_base+213

// ---------------------------------------------------------------------------
// Kernel 1: lse[b,i] = logsumexp(pred_cat[b,i,:]) over C=92 classes
// ---------------------------------------------------------------------------
__global__ void lse_kernel(const float* __restrict__ pc, float* __restrict__ lse) {
    int idx = blockIdx.x * blockDim.x + threadIdx.x;  // over B*Q
    if (idx >= BB * QQ) return;
    const float* row = pc + (size_t)idx * CC;
    float m = -INFINITY;
    for (int c = 0; c < CC; ++c) m = fmaxf(m, row[c]);
    float s = 0.f;
    for (int c = 0; c < CC; ++c) s += expf(row[c] - m);
    lse[idx] = m + logf(s);
}

// ---------------------------------------------------------------------------
// Kernel 2: cost[b,i,j] = CE + SmoothL1*mask
// ---------------------------------------------------------------------------
__global__ void cost_kernel(const float* __restrict__ pc,
                            const float* __restrict__ pb,
                            const int*   __restrict__ tc,
                            const float* __restrict__ tb,
                            const float* __restrict__ lse,
                            float* __restrict__ cost) {
    long idx = blockIdx.x * (long)blockDim.x + threadIdx.x;
    if (idx >= (long)BB * QQ * QQ) return;
    int j = (int)(idx % QQ);
    int i = (int)((idx / QQ) % QQ);
    int b = (int)(idx / ((long)QQ * QQ));
    int cls = tc[b * QQ + j];
    float ce = lse[b * QQ + i] - pc[((size_t)(b * QQ + i)) * CC + cls];
    const float* pbb = pb + ((size_t)(b * QQ + i)) * 4;
    const float* tbb = tb + ((size_t)(b * QQ + j)) * 4;
    float sl1 = 0.f;
#pragma unroll
    for (int k = 0; k < 4; ++k) {
        float d = pbb[k] - tbb[k];
        float ad = fabsf(d);
        sl1 += (ad < 1.f) ? 0.5f * d * d : (ad - 0.5f);
    }
    float mask = (cls != 0) ? 1.f : 0.f;
    cost[idx] = ce + sl1 * mask;
}

// ---------------------------------------------------------------------------
__device__ __forceinline__ int rdlane_i(int x, int l) { return __builtin_amdgcn_readlane(x, l); }
__device__ __forceinline__ float rdlane_f(float x, int l) {
    return __uint_as_float((unsigned)__builtin_amdgcn_readlane((int)__float_as_uint(x), l));
}

// wave64 float min-reduce via DPP (row_shr 1/2/4/8, row_bcast 15/31), result
// broadcast from lane 63 as an SGPR. (validated R9)
__device__ __forceinline__ float wave_fmin_bcast(float x) {
    float y;
#define DPPSTEP(ctrl) \
    y = __uint_as_float((unsigned)__builtin_amdgcn_update_dpp( \
            (int)__float_as_uint(x), (int)__float_as_uint(x), ctrl, 0xf, 0xf, false)); \
    x = fminf(x, y);
    DPPSTEP(0x111) DPPSTEP(0x112) DPPSTEP(0x114) DPPSTEP(0x118)
    DPPSTEP(0x142) DPPSTEP(0x143)
#undef DPPSTEP
    return rdlane_f(x, 63);
}

// ---------------------------------------------------------------------------
// Kernel 3: Hungarian (e-maxx JV, reference trajectory bit-for-bit) — one
// 64-lane wave per batch. R10 pipeline restructure (same arithmetic):
//  - sigma-permuted LDS layout: C[i][c] stored at cm[i*200 + 50*(c&3) + c/4]
//    => lane t (t<50) OWNS columns j=4t+1..4t+4 (j is (t,k)-lexicographic:
//    ONE ballot + lowest-slot = exact jnp.argmin tie-break), while physical
//    reads are stride-1 b32 at 50m+t — conflict-free (R7's b128 trap avoided).
//  - premin overlap: gmin = min(masked cur, masked minv_old); min is exactly
//    associative, so "local min over k of masked minv_old" (premin) is
//    computed in the PREVIOUS load-latency window. Post-load critical path:
//    cur=(c-u0)-v -> mask -> localmin -> fmin(premin) -> DPP. The minv/waysl
//    merge (gated on pre-j1 used mask, == reference order) and the -=delta
//    updates run in the next window, overlapped with the ds_read latency.
//  - candidates (j, pslot, uslot) pre-selected per-lane during DPP; after
//    ctz: 3 independent readlanes -> address -> issue next row's loads.
// Idle lanes t>=50 are permanently masked via usedm=0xF. LDS immutable after
// staging => prefetch is deterministic. u/p/way/v all in registers.
// ---------------------------------------------------------------------------
__global__ __launch_bounds__(64) void hungarian_kernel(const float* __restrict__ cost,
                                                       float* __restrict__ out) {
    const int b = blockIdx.x;
    const int t = threadIdx.x;
    const float* cb = cost + (size_t)b * QQ * QQ;

    __shared__ __align__(16) float cm[CMPAD];

    // stage with sigma permutation: C[i][4c4+m] -> cm[i*200 + 50m + c4].
    // global reads stay float4-coalesced; LDS writes stride-1 across lanes.
    {
        const float4* src = (const float4*)cb;
        for (int idx = t; idx < QQ * QQ / 4; idx += 64) {
            int i  = idx / 50;
            int c4 = idx % 50;
            float4 val = src[idx];
            float* rowp = cm + i * QQ;
            rowp[c4]        = val.x;
            rowp[50 + c4]   = val.y;
            rowp[100 + c4]  = val.z;
            rowp[150 + c4]  = val.w;
        }
    }

    const float INF = 1e9f;

    float v[4]     = {0.f, 0.f, 0.f, 0.f};
    int   pslot[4] = {0, 0, 0, 0};          // row matched to owned column (0=free)
    float uslot[4] = {0.f, 0.f, 0.f, 0.f};  // u of that row
    float minv[4];
    float mminv[4];                         // used-masked minv (window-computed)
    int   waysl[4];
    int   usedm;
    float usent;

    for (int i = 1; i <= QQ; ++i) {
        minv[0] = minv[1] = minv[2] = minv[3] = INF;
        mminv[0] = mminv[1] = mminv[2] = mminv[3] = INF;
        waysl[0] = waysl[1] = waysl[2] = waysl[3] = 0;
        usedm = (t < 50) ? 0 : 0xF;         // idle lanes permanently masked
        usent = 0.f;                        // u[i] == 0 at phase start
        float premin = INF;                 // min over k of mminv
        int j0 = 0;
        float u0 = 0.f;                     // u[i0], i0 = i
        // prologue: issue loads for row i
        const float* crow = cm + (i - 1) * QQ;
        float c0 = crow[t];
        float c1 = crow[50 + t];
        float c2 = crow[100 + t];
        float c3 = crow[150 + t];

        for (;;) {
            // ---- post-load critical path: cur -> mask -> localmin -> DPP
            float cur0 = (c0 - u0) - v[0];              // ref op order
            float cur1 = (c1 - u0) - v[1];
            float cur2 = (c2 - u0) - v[2];
            float cur3 = (c3 - u0) - v[3];
            float m0 = (usedm & 1) ? INF : cur0;
            float m1 = (usedm & 2) ? INF : cur1;
            float m2 = (usedm & 4) ? INF : cur2;
            float m3 = (usedm & 8) ? INF : cur3;
            float x = fminf(fminf(fminf(m0, m1), fminf(m2, m3)), premin);
            float gmin = wave_fmin_bcast(x);
            float delta = gmin;

            // ---- per-slot kv + candidates (overlap the DPP chain)
            float kv0 = fminf(m0, mminv[0]);
            float kv1 = fminf(m1, mminv[1]);
            float kv2 = fminf(m2, mminv[2]);
            float kv3 = fminf(m3, mminv[3]);
            int lk = (kv0 == gmin) ? 0 : (kv1 == gmin) ? 1 : (kv2 == gmin) ? 2 : 3;
            int   cj = 4 * t + lk + 1;
            int   cp = (lk == 0) ? pslot[0] : (lk == 1) ? pslot[1]
                      : (lk == 2) ? pslot[2] : pslot[3];
            float cu = (lk == 0) ? uslot[0] : (lk == 1) ? uslot[1]
                      : (lk == 2) ? uslot[2] : uslot[3];

            unsigned long long mm = __ballot(x == gmin);
            int ts = (int)__builtin_ctzll(mm);
            int   j1  = rdlane_i(cj, ts);
            int   pi  = rdlane_i(cp, ts);
            float u0n = rdlane_f(cu, ts);

            // ---- issue next row's loads NOW (cm immutable: deterministic)
            int nr = (pi > 0 ? pi : 1) - 1;
            const float* nrow = cm + nr * QQ;
            float n0 = nrow[t];
            float n1 = nrow[50 + t];
            float n2 = nrow[100 + t];
            float n3 = nrow[150 + t];

            // ---- window work (overlaps load latency):
            // merge cur into minv/waysl, gated on PRE-j1 used mask (== ref)
            if (!(usedm & 1) && cur0 < minv[0]) { minv[0] = cur0; waysl[0] = j0; }
            if (!(usedm & 2) && cur1 < minv[1]) { minv[1] = cur1; waysl[1] = j0; }
            if (!(usedm & 4) && cur2 < minv[2]) { minv[2] = cur2; waysl[2] = j0; }
            if (!(usedm & 8) && cur3 < minv[3]) { minv[3] = cur3; waysl[3] = j0; }
            // updates (identical fp-op sequence to reference)
#pragma unroll
            for (int k = 0; k < 4; ++k) {
                if (usedm & (1 << k)) {
                    v[k] -= delta;
                    uslot[k] += delta;               // == u[p[j]] += delta
                } else {
                    minv[k] -= delta;
                }
            }
            usent += delta;                          // == u[i] += delta

            if (pi == 0) { j0 = j1; break; }

            // mark j1 used (owner lane = ts, slot = its lk)
            if (t == ts) usedm |= 1 << lk;
            // masked minv + premin for next iteration
            mminv[0] = (usedm & 1) ? INF : minv[0];
            mminv[1] = (usedm & 2) ? INF : minv[1];
            mminv[2] = (usedm & 4) ? INF : minv[2];
            mminv[3] = (usedm & 8) ? INF : minv[3];
            premin = fminf(fminf(mminv[0], mminv[1]), fminf(mminv[2], mminv[3]));

            j0 = j1; u0 = u0n;
            c0 = n0; c1 = n1; c2 = n2; c3 = n3;
        }

        // ---- augment: flip matching along alternating path (uniform walk;
        //      way/p/u served from registers via readlane; entries frozen)
        {
            int jj = j0;
            while (jj != 0) {
                int jm = jj - 1, lm = jm >> 2, sm = jm & 3;
                int ws = (sm == 0) ? waysl[0] : (sm == 1) ? waysl[1]
                        : (sm == 2) ? waysl[2] : waysl[3];
                int jn = rdlane_i(ws, lm);
                int pnew; float unew;
                if (jn == 0) {
                    pnew = i;                        // p[0] = i (sentinel)
                    unew = usent;                    // u[i] accumulated this phase
                } else {
                    int jm2 = jn - 1, ln2 = jm2 >> 2, sn = jm2 & 3;
                    int   ps2 = (sn == 0) ? pslot[0] : (sn == 1) ? pslot[1]
                               : (sn == 2) ? pslot[2] : pslot[3];
                    float us2 = (sn == 0) ? uslot[0] : (sn == 1) ? uslot[1]
                               : (sn == 2) ? uslot[2] : uslot[3];
                    pnew = rdlane_i(ps2, ln2);
                    unew = rdlane_f(us2, ln2);
                }
                if (lm == t) { pslot[sm] = pnew; uslot[sm] = unew; }
                jj = jn;
            }
        }
    }

    // pslot[k] = row matched to owned column j=4t+k+1; emit per-row cost
    if (t < 50) {
#pragma unroll
        for (int k = 0; k < 4; ++k) {
            int row = pslot[k] - 1;
            out[b * QQ + row] = cm[row * QQ + 50 * k + t];  // == C[row][4t+k]
        }
    }
}

// ---------------------------------------------------------------------------
extern "C" void kernel_launch(void* const* d_in, const int* in_sizes, int n_in,
                              void* d_out, int out_size, void* d_ws, size_t ws_size,
                              hipStream_t stream) {
    const float* pred_cat  = (const float*)d_in[0];
    const float* pred_bbox = (const float*)d_in[1];
    const int*   tar_cat   = (const int*)d_in[2];
    const float* tar_bbox  = (const float*)d_in[3];
    float* out = (float*)d_out;

    float* cost = (float*)d_ws;                     // B*Q*Q floats = 20.48 MB
    float* lse  = cost + (size_t)BB * QQ * QQ;      // B*Q floats

    lse_kernel<<<(BB * QQ + 255) / 256, 256, 0, stream>>>(pred_cat, lse);
    cost_kernel<<<((long)BB * QQ * QQ + 255) / 256, 256, 0, stream>>>(
        pred_cat, pred_bbox, tar_cat, tar_bbox, lse, cost);
    hungarian_kernel<<<BB, 64, 0, stream>>>(cost, out);
}

// Round 11
// 1608.430 us; speedup vs baseline: 1.1434x; 1.1434x over previous
//
#include <hip/hip_runtime.h>
#include <math.h>

#define BB 128
#define QQ 200
#define CC 92
#define CMPAD (QQ * QQ + 64) // pad so c3 = crow[192+t] stays in-bounds for t<64

// ---------------------------------------------------------------------------
// Kernel 1: lse[b,i] = logsumexp(pred_cat[b,i,:]) over C=92 classes
// ---------------------------------------------------------------------------
__global__ void lse_kernel(const float* __restrict__ pc, float* __restrict__ lse) {
    int idx = blockIdx.x * blockDim.x + threadIdx.x;  // over B*Q
    if (idx >= BB * QQ) return;
    const float* row = pc + (size_t)idx * CC;
    float m = -INFINITY;
    for (int c = 0; c < CC; ++c) m = fmaxf(m, row[c]);
    float s = 0.f;
    for (int c = 0; c < CC; ++c) s += expf(row[c] - m);
    lse[idx] = m + logf(s);
}

// ---------------------------------------------------------------------------
// Kernel 2: cost[b,i,j] = CE + SmoothL1*mask
// ---------------------------------------------------------------------------
__global__ void cost_kernel(const float* __restrict__ pc,
                            const float* __restrict__ pb,
                            const int*   __restrict__ tc,
                            const float* __restrict__ tb,
                            const float* __restrict__ lse,
                            float* __restrict__ cost) {
    long idx = blockIdx.x * (long)blockDim.x + threadIdx.x;
    if (idx >= (long)BB * QQ * QQ) return;
    int j = (int)(idx % QQ);
    int i = (int)((idx / QQ) % QQ);
    int b = (int)(idx / ((long)QQ * QQ));
    int cls = tc[b * QQ + j];
    float ce = lse[b * QQ + i] - pc[((size_t)(b * QQ + i)) * CC + cls];
    const float* pbb = pb + ((size_t)(b * QQ + i)) * 4;
    const float* tbb = tb + ((size_t)(b * QQ + j)) * 4;
    float sl1 = 0.f;
#pragma unroll
    for (int k = 0; k < 4; ++k) {
        float d = pbb[k] - tbb[k];
        float ad = fabsf(d);
        sl1 += (ad < 1.f) ? 0.5f * d * d : (ad - 0.5f);
    }
    float mask = (cls != 0) ? 1.f : 0.f;
    cost[idx] = ce + sl1 * mask;
}

// ---------------------------------------------------------------------------
__device__ __forceinline__ int rdlane_i(int x, int l) { return __builtin_amdgcn_readlane(x, l); }
__device__ __forceinline__ float rdlane_f(float x, int l) {
    return __uint_as_float((unsigned)__builtin_amdgcn_readlane((int)__float_as_uint(x), l));
}

// wave64 float min-reduce via DPP (row_shr 1/2/4/8, row_bcast 15/31), result
// broadcast from lane 63 as an SGPR. (validated R9)
__device__ __forceinline__ float wave_fmin_bcast(float x) {
    float y;
#define DPPSTEP(ctrl) \
    y = __uint_as_float((unsigned)__builtin_amdgcn_update_dpp( \
            (int)__float_as_uint(x), (int)__float_as_uint(x), ctrl, 0xf, 0xf, false)); \
    x = fminf(x, y);
    DPPSTEP(0x111) DPPSTEP(0x112) DPPSTEP(0x114) DPPSTEP(0x118)
    DPPSTEP(0x142) DPPSTEP(0x143)
#undef DPPSTEP
    return rdlane_f(x, 63);
}

// ---------------------------------------------------------------------------
// Kernel 3: Hungarian — textbook JV shortest-augmenting-path with ABSOLUTE
// distances (duals frozen per phase), one 64-lane wave per batch.
// R11 rationale (R10 post-mortem): the loop is VALU-issue-bound, so the
// per-iteration dual updates of the e-maxx relative form (~25 VALU/iter:
// v-=delta, u+=delta, minv-=delta under per-slot masks) are replaced by a
// once-per-PHASE epilogue:
//   iter:  d[j] = min(d[j], (C[i0][j] + s) - v[j]),  s = mu - u[i0] (uniform)
//   select j1 = argmin_{unused} d  (DPP fmin + ballots, k-major smallest-j)
//   end:   for used j: adj = muF - d[j] (d frozen at selection = mu_j);
//          v[j] -= adj; u[row(j)] += adj; u[sentinel row] = muF.
// Exactly equivalent to e-maxx's accumulated deltas in real arithmetic;
// fp trajectory differs, but the OUTPUT depends only on the assignment,
// which is robust here (R3: a different-trajectory exact JV matched the
// reference assignment bitwise; exact ties occur only between identical
// tar_cat==0 columns, where any permutation gives bit-equal output).
// Kept from R5-R9 (all validated): k-major layout (lane t owns j=1+t+64k,
// stride-1 conflict-free b32 LDS reads), immutable-LDS prefetch after pi
// (deterministic), register-resident p/u/way via readlane, augment walk.
// ---------------------------------------------------------------------------
__global__ __launch_bounds__(64) void hungarian_kernel(const float* __restrict__ cost,
                                                       float* __restrict__ out) {
    const int b = blockIdx.x;
    const int t = threadIdx.x;
    const float* cb = cost + (size_t)b * QQ * QQ;

    __shared__ __align__(16) float cm[CMPAD];

    // stage cost matrix into LDS (float4; single wave => in-order DS ops)
    {
        const float4* src = (const float4*)cb;
        float4* dst = (float4*)cm;
        for (int idx = t; idx < QQ * QQ / 4; idx += 64) dst[idx] = src[idx];
    }

    const float INF = 1e9f;
    const int nval  = (t < 8) ? 4 : 3;   // slot k valid iff 1+t+64k <= 200
    const int initm = (t < 8) ? 0 : 8;   // slot-3 invalid => permanently "used"

    float v[4]     = {0.f, 0.f, 0.f, 0.f};
    int   pslot[4] = {0, 0, 0, 0};          // row matched to owned column (0=free)
    float uslot[4] = {0.f, 0.f, 0.f, 0.f};  // u of that row
    float d[4];                              // absolute Dijkstra distance
    int   way[4];
    int   usedm;

    for (int i = 1; i <= QQ; ++i) {
        d[0] = d[1] = d[2] = d[3] = INF;
        way[0] = way[1] = way[2] = way[3] = 0;
        usedm = initm;
        float s = 0.f;                  // mu - u[i0]; first row: mu=0, u[i]=0
        int j0 = 0;
        const float* crow = cm + (i - 1) * QQ;
        float c0 = crow[t];
        float c1 = crow[64 + t];
        float c2 = crow[128 + t];
        float c3 = crow[192 + t];       // pad keeps this in-bounds
        float muF;

        for (;;) {
            // ---- mark j0 used (owner lane)
            if (j0 > 0) {
                int sl = (j0 - 1) >> 6;
                if (((j0 - 1) & 63) == t) usedm |= 1 << sl;
            }

            // ---- relax owned columns (duals frozen; d/way freeze once used)
            float nd0 = (c0 + s) - v[0];
            float nd1 = (c1 + s) - v[1];
            float nd2 = (c2 + s) - v[2];
            float nd3 = (c3 + s) - v[3];
            if (!(usedm & 1) && nd0 < d[0]) { d[0] = nd0; way[0] = j0; }
            if (!(usedm & 2) && nd1 < d[1]) { d[1] = nd1; way[1] = j0; }
            if (!(usedm & 4) && nd2 < d[2]) { d[2] = nd2; way[2] = j0; }
            if (!(usedm & 8) && nd3 < d[3]) { d[3] = nd3; way[3] = j0; }
            float kv0 = (usedm & 1) ? INF : d[0];
            float kv1 = (usedm & 2) ? INF : d[1];
            float kv2 = (usedm & 4) ? INF : d[2];
            float kv3 = (usedm & 8) ? INF : d[3];

            float gmin = wave_fmin_bcast(fminf(fminf(kv0, kv1), fminf(kv2, kv3)));

            // ---- smallest j with kv==gmin: k-major, lowest lane (scalar chain)
            unsigned long long m0 = __ballot(kv0 == gmin);
            unsigned long long m1 = __ballot(kv1 == gmin);
            unsigned long long m2 = __ballot(kv2 == gmin);
            unsigned long long m3 = __ballot(kv3 == gmin);
            int j1;
            if (m0)      j1 = 1   + (int)__builtin_ctzll(m0);
            else if (m1) j1 = 65  + (int)__builtin_ctzll(m1);
            else if (m2) j1 = 129 + (int)__builtin_ctzll(m2);
            else         j1 = 193 + (int)__builtin_ctzll(m3);

            // ---- matched row + its (phase-frozen) dual from j1's owner lane
            int kk = (j1 - 1) >> 6, ln = (j1 - 1) & 63;
            int   ps = (kk == 0) ? pslot[0] : (kk == 1) ? pslot[1]
                      : (kk == 2) ? pslot[2] : pslot[3];
            float us = (kk == 0) ? uslot[0] : (kk == 1) ? uslot[1]
                      : (kk == 2) ? uslot[2] : uslot[3];
            int pi = rdlane_i(ps, ln);

            // ---- issue next row's loads NOW (cm immutable: deterministic)
            int nr = (pi > 0 ? pi : 1) - 1;
            const float* nrow = cm + nr * QQ;
            float n0 = nrow[t];
            float n1 = nrow[64 + t];
            float n2 = nrow[128 + t];
            float n3 = nrow[192 + t];

            float u0n = rdlane_f(us, ln);

            if (pi == 0) { j0 = j1; muF = gmin; break; }

            s = gmin - u0n;                  // mu - u[i0] for next iteration
            j0 = j1;
            c0 = n0; c1 = n1; c2 = n2; c3 = n3;
        }

        // ---- phase epilogue: dual updates for slots used THIS phase
        // (d[k] frozen at selection == mu_k; final column j1 excluded — it
        // was never marked used, matching e-maxx where its v is untouched)
        {
            int pu = usedm & ~initm;
            if (pu & 1) { float a = muF - d[0]; v[0] -= a; uslot[0] += a; }
            if (pu & 2) { float a = muF - d[1]; v[1] -= a; uslot[1] += a; }
            if (pu & 4) { float a = muF - d[2]; v[2] -= a; uslot[2] += a; }
            if (pu & 8) { float a = muF - d[3]; v[3] -= a; uslot[3] += a; }
        }
        float usent = muF;                   // u of sentinel row i (was 0)

        // ---- augment: flip matching along alternating path (uniform walk;
        //      way/p/u served from registers via readlane; entries frozen)
        {
            int jj = j0;
            while (jj != 0) {
                int jm = jj - 1, km = jm >> 6, lm = jm & 63;
                int ws = (km == 0) ? way[0] : (km == 1) ? way[1]
                        : (km == 2) ? way[2] : way[3];
                int jn = rdlane_i(ws, lm);
                int pnew; float unew;
                if (jn == 0) {
                    pnew = i;                        // p[0] = i (sentinel)
                    unew = usent;
                } else {
                    int jm2 = jn - 1, kn = jm2 >> 6, ln2 = jm2 & 63;
                    int   ps2 = (kn == 0) ? pslot[0] : (kn == 1) ? pslot[1]
                               : (kn == 2) ? pslot[2] : pslot[3];
                    float us2 = (kn == 0) ? uslot[0] : (kn == 1) ? uslot[1]
                               : (kn == 2) ? uslot[2] : uslot[3];
                    pnew = rdlane_i(ps2, ln2);
                    unew = rdlane_f(us2, ln2);
                }
                if (lm == t) { pslot[km] = pnew; uslot[km] = unew; }
                jj = jn;
            }
        }
    }

    // pslot[k] = row matched to owned column jc; emit per-row matched cost
#pragma unroll
    for (int k = 0; k < 4; ++k) {
        if (k < nval) {
            int jc = 1 + t + 64 * k;
            int row = pslot[k] - 1;
            out[b * QQ + row] = cm[row * QQ + (jc - 1)];
        }
    }
}

// ---------------------------------------------------------------------------
extern "C" void kernel_launch(void* const* d_in, const int* in_sizes, int n_in,
                              void* d_out, int out_size, void* d_ws, size_t ws_size,
                              hipStream_t stream) {
    const float* pred_cat  = (const float*)d_in[0];
    const float* pred_bbox = (const float*)d_in[1];
    const int*   tar_cat   = (const int*)d_in[2];
    const float* tar_bbox  = (const float*)d_in[3];
    float* out = (float*)d_out;

    float* cost = (float*)d_ws;                     // B*Q*Q floats = 20.48 MB
    float* lse  = cost + (size_t)BB * QQ * QQ;      // B*Q floats

    lse_kernel<<<(BB * QQ + 255) / 256, 256, 0, stream>>>(pred_cat, lse);
    cost_kernel<<<((long)BB * QQ * QQ + 255) / 256, 256, 0, stream>>>(
        pred_cat, pred_bbox, tar_cat, tar_bbox, lse, cost);
    hungarian_kernel<<<BB, 64, 0, stream>>>(cost, out);
}

// Round 12
// 1534.578 us; speedup vs baseline: 1.1985x; 1.0481x over previous
//
#include <hip/hip_runtime.h>
#include <math.h>

#define BB 128
#define QQ 200
#define CC 92
#define CMPAD (QQ * QQ + 64) // pad so c3 = crow[192+t] stays in-bounds for t<64

// ---------------------------------------------------------------------------
// Kernel 1: lse[b,i] = logsumexp(pred_cat[b,i,:]) over C=92 classes
// ---------------------------------------------------------------------------
__global__ void lse_kernel(const float* __restrict__ pc, float* __restrict__ lse) {
    int idx = blockIdx.x * blockDim.x + threadIdx.x;  // over B*Q
    if (idx >= BB * QQ) return;
    const float* row = pc + (size_t)idx * CC;
    float m = -INFINITY;
    for (int c = 0; c < CC; ++c) m = fmaxf(m, row[c]);
    float s = 0.f;
    for (int c = 0; c < CC; ++c) s += expf(row[c] - m);
    lse[idx] = m + logf(s);
}

// ---------------------------------------------------------------------------
// Kernel 2 (v2): cost[b,i,j] = CE + SmoothL1*mask. Block = (i, b) from
// blockIdx (NO integer division), thread j. Same fp expression order as v1
// => bit-identical cost matrix. pc row + pbb are L1-resident per block;
// tbb and the output are coalesced.
// ---------------------------------------------------------------------------
__global__ __launch_bounds__(256) void cost_kernel2(const float* __restrict__ pc,
                                                    const float* __restrict__ pb,
                                                    const int*   __restrict__ tc,
                                                    const float* __restrict__ tb,
                                                    const float* __restrict__ lse,
                                                    float* __restrict__ cost) {
    const int i = blockIdx.x;      // query index 0..QQ-1
    const int b = blockIdx.y;      // batch index
    const int j = threadIdx.x;
    if (j >= QQ) return;
    const int base = b * QQ;
    const float l = lse[base + i];
    const float* pcrow = pc + (size_t)(base + i) * CC;
    const float4 pbb = *(const float4*)(pb + (size_t)(base + i) * 4);
    const int cls = tc[base + j];
    const float ce = l - pcrow[cls];
    const float4 tbb = *(const float4*)(tb + (size_t)(base + j) * 4);
    float sl1 = 0.f;
    {
        float d, ad;
        d = pbb.x - tbb.x; ad = fabsf(d); sl1 += (ad < 1.f) ? 0.5f * d * d : (ad - 0.5f);
        d = pbb.y - tbb.y; ad = fabsf(d); sl1 += (ad < 1.f) ? 0.5f * d * d : (ad - 0.5f);
        d = pbb.z - tbb.z; ad = fabsf(d); sl1 += (ad < 1.f) ? 0.5f * d * d : (ad - 0.5f);
        d = pbb.w - tbb.w; ad = fabsf(d); sl1 += (ad < 1.f) ? 0.5f * d * d : (ad - 0.5f);
    }
    const float mask = (cls != 0) ? 1.f : 0.f;
    cost[(size_t)(base + i) * QQ + j] = ce + sl1 * mask;
}

// ---------------------------------------------------------------------------
__device__ __forceinline__ int rdlane_i(int x, int l) { return __builtin_amdgcn_readlane(x, l); }
__device__ __forceinline__ float rdlane_f(float x, int l) {
    return __uint_as_float((unsigned)__builtin_amdgcn_readlane((int)__float_as_uint(x), l));
}

// wave64 float min-reduce via DPP (row_shr 1/2/4/8, row_bcast 15/31), result
// broadcast from lane 63 as an SGPR. (validated R9)
__device__ __forceinline__ float wave_fmin_bcast(float x) {
    float y;
#define DPPSTEP(ctrl) \
    y = __uint_as_float((unsigned)__builtin_amdgcn_update_dpp( \
            (int)__float_as_uint(x), (int)__float_as_uint(x), ctrl, 0xf, 0xf, false)); \
    x = fminf(x, y);
    DPPSTEP(0x111) DPPSTEP(0x112) DPPSTEP(0x114) DPPSTEP(0x118)
    DPPSTEP(0x142) DPPSTEP(0x143)
#undef DPPSTEP
    return rdlane_f(x, 63);
}

// ---------------------------------------------------------------------------
// Kernel 3: Hungarian (e-maxx JV, R9 trajectory bit-for-bit) — one 64-lane
// wave per batch. R12 chain trim (loop period = chain + max(0, L - shadow)):
//  - selection kv = used ? INF : fmin(minv_old, cur): the DPP reduce no
//    longer waits for the minv/way merge cndmask; the merge runs in the
//    post-load-issue SHADOW with the pre-j1 used mask (same fp op sequence
//    as R9's top-of-loop merge, just scheduled later).
//  - mark-used moved to iteration bottom (== R9's top-mark of next iter).
//  - invalid slot 3 (t>=8) folded into usedm bit 3: no t<8 tests on chain.
// Kept from R8/R9 (all validated): k-major layout (lane t owns j=1+t+64k,
// stride-1 conflict-free b32 LDS reads), immutable-LDS prefetch after pi
// (deterministic), register-resident p/u/way via readlane, per-iteration
// dual updates in the load shadow, augment walk via readlane.
// ---------------------------------------------------------------------------
__global__ __launch_bounds__(64) void hungarian_kernel(const float* __restrict__ cost,
                                                       float* __restrict__ out) {
    const int b = blockIdx.x;
    const int t = threadIdx.x;
    const float* cb = cost + (size_t)b * QQ * QQ;

    __shared__ __align__(16) float cm[CMPAD];

    // stage cost matrix into LDS (float4; single wave => in-order DS ops)
    {
        const float4* src = (const float4*)cb;
        float4* dst = (float4*)cm;
        for (int idx = t; idx < QQ * QQ / 4; idx += 64) dst[idx] = src[idx];
    }

    const float INF = 1e9f;
    const int nval  = (t < 8) ? 4 : 3;   // slot k valid iff 1+t+64k <= 200
    const int initm = (t < 8) ? 0 : 8;   // invalid slot 3 permanently "used"

    float v[4]     = {0.f, 0.f, 0.f, 0.f};
    int   pslot[4] = {0, 0, 0, 0};          // row matched to owned column (0=free)
    float uslot[4] = {0.f, 0.f, 0.f, 0.f};  // u of that row
    float minv[4];
    int   waysl[4];
    int   usedm;
    float usent;

    for (int i = 1; i <= QQ; ++i) {
        minv[0] = minv[1] = minv[2] = minv[3] = INF;
        waysl[0] = waysl[1] = waysl[2] = waysl[3] = 0;
        usedm = initm;
        usent = 0.f;                    // u[i] == 0 at phase start
        int j0 = 0;
        float u0 = 0.f;                 // u[i0], i0 = i first
        const float* crow = cm + (i - 1) * QQ;
        float c0 = crow[t];
        float c1 = crow[64 + t];
        float c2 = crow[128 + t];
        float c3 = crow[192 + t];       // pad keeps this in-bounds

        for (;;) {
            // ---- chain: cur -> kv (no merge wait) -> local min -> DPP
            float cur0 = (c0 - u0) - v[0];
            float cur1 = (c1 - u0) - v[1];
            float cur2 = (c2 - u0) - v[2];
            float cur3 = (c3 - u0) - v[3];
            float kv0 = (usedm & 1) ? INF : fminf(minv[0], cur0);
            float kv1 = (usedm & 2) ? INF : fminf(minv[1], cur1);
            float kv2 = (usedm & 4) ? INF : fminf(minv[2], cur2);
            float kv3 = (usedm & 8) ? INF : fminf(minv[3], cur3);
            float gmin = wave_fmin_bcast(fminf(fminf(kv0, kv1), fminf(kv2, kv3)));
            float delta = gmin;

            // ---- smallest j with kv==gmin: k-major, lowest lane
            unsigned long long m0 = __ballot(kv0 == gmin);
            unsigned long long m1 = __ballot(kv1 == gmin);
            unsigned long long m2 = __ballot(kv2 == gmin);
            unsigned long long m3 = __ballot(kv3 == gmin);
            int j1;
            if (m0)      j1 = 1   + (int)__builtin_ctzll(m0);
            else if (m1) j1 = 65  + (int)__builtin_ctzll(m1);
            else if (m2) j1 = 129 + (int)__builtin_ctzll(m2);
            else         j1 = 193 + (int)__builtin_ctzll(m3);

            // ---- matched row + its dual from j1's owner lane (j1 uniform)
            int kk = (j1 - 1) >> 6, ln = (j1 - 1) & 63;
            int   ps = (kk == 0) ? pslot[0] : (kk == 1) ? pslot[1]
                      : (kk == 2) ? pslot[2] : pslot[3];
            float us = (kk == 0) ? uslot[0] : (kk == 1) ? uslot[1]
                      : (kk == 2) ? uslot[2] : uslot[3];
            int pi = rdlane_i(ps, ln);

            // ---- issue next row's loads NOW (cm immutable: deterministic)
            int nr = (pi > 0 ? pi : 1) - 1;
            const float* nrow = cm + nr * QQ;
            float n0 = nrow[t];
            float n1 = nrow[64 + t];
            float n2 = nrow[128 + t];
            float n3 = nrow[192 + t];

            float u0n = rdlane_f(us, ln);

            // ---- SHADOW: merge (pre-j1 usedm == R9's top-merge), updates
            if (!(usedm & 1) && cur0 < minv[0]) { minv[0] = cur0; waysl[0] = j0; }
            if (!(usedm & 2) && cur1 < minv[1]) { minv[1] = cur1; waysl[1] = j0; }
            if (!(usedm & 4) && cur2 < minv[2]) { minv[2] = cur2; waysl[2] = j0; }
            if (!(usedm & 8) && cur3 < minv[3]) { minv[3] = cur3; waysl[3] = j0; }
#pragma unroll
            for (int k = 0; k < 4; ++k) {
                if (usedm & (1 << k)) {
                    v[k] -= delta;                   // junk for invalid slot3
                    uslot[k] += delta;               //   (never read) — harmless
                } else {
                    minv[k] -= delta;
                }
            }
            usent += delta;                          // == u[i] += delta

            if (pi == 0) { j0 = j1; break; }

            // ---- mark j1 used (owner lane) — == R9's next-iter top-mark
            if (ln == t) usedm |= 1 << kk;
            j0 = j1; u0 = u0n;
            c0 = n0; c1 = n1; c2 = n2; c3 = n3;
        }

        // ---- augment: flip matching along alternating path (uniform walk;
        //      way/p/u served from registers via readlane; entries frozen)
        {
            int jj = j0;
            while (jj != 0) {
                int jm = jj - 1, km = jm >> 6, lm = jm & 63;
                int ws = (km == 0) ? waysl[0] : (km == 1) ? waysl[1]
                        : (km == 2) ? waysl[2] : waysl[3];
                int jn = rdlane_i(ws, lm);
                int pnew; float unew;
                if (jn == 0) {
                    pnew = i;                        // p[0] = i (sentinel)
                    unew = usent;                    // u[i] accumulated this phase
                } else {
                    int jm2 = jn - 1, kn = jm2 >> 6, ln2 = jm2 & 63;
                    int   ps2 = (kn == 0) ? pslot[0] : (kn == 1) ? pslot[1]
                               : (kn == 2) ? pslot[2] : pslot[3];
                    float us2 = (kn == 0) ? uslot[0] : (kn == 1) ? uslot[1]
                               : (kn == 2) ? uslot[2] : uslot[3];
                    pnew = rdlane_i(ps2, ln2);
                    unew = rdlane_f(us2, ln2);
                }
                if (lm == t) { pslot[km] = pnew; uslot[km] = unew; }
                jj = jn;
            }
        }
    }

    // pslot[k] = row matched to owned column jc; emit per-row matched cost
#pragma unroll
    for (int k = 0; k < 4; ++k) {
        if (k < nval) {
            int jc = 1 + t + 64 * k;
            int row = pslot[k] - 1;
            out[b * QQ + row] = cm[row * QQ + (jc - 1)];
        }
    }
}

// ---------------------------------------------------------------------------
extern "C" void kernel_launch(void* const* d_in, const int* in_sizes, int n_in,
                              void* d_out, int out_size, void* d_ws, size_t ws_size,
                              hipStream_t stream) {
    const float* pred_cat  = (const float*)d_in[0];
    const float* pred_bbox = (const float*)d_in[1];
    const int*   tar_cat   = (const int*)d_in[2];
    const float* tar_bbox  = (const float*)d_in[3];
    float* out = (float*)d_out;

    float* cost = (float*)d_ws;                     // B*Q*Q floats = 20.48 MB
    float* lse  = cost + (size_t)BB * QQ * QQ;      // B*Q floats

    lse_kernel<<<(BB * QQ + 255) / 256, 256, 0, stream>>>(pred_cat, lse);
    cost_kernel2<<<dim3(QQ, BB), 256, 0, stream>>>(
        pred_cat, pred_bbox, tar_cat, tar_bbox, lse, cost);
    hungarian_kernel<<<BB, 64, 0, stream>>>(cost, out);
}

// Round 13
// 1502.383 us; speedup vs baseline: 1.2241x; 1.0214x over previous
//
#include <hip/hip_runtime.h>
#include <math.h>

#define BB 128
#define QQ 200
#define CC 92
#define CMPAD (QQ * QQ + 64) // pad so c3 = crow[192+t] stays in-bounds for t<64

// ---------------------------------------------------------------------------
__device__ __forceinline__ int rdlane_i(int x, int l) { return __builtin_amdgcn_readlane(x, l); }
__device__ __forceinline__ float rdlane_f(float x, int l) {
    return __uint_as_float((unsigned)__builtin_amdgcn_readlane((int)__float_as_uint(x), l));
}

// wave64 float min-reduce via DPP (row_shr 1/2/4/8, row_bcast 15/31), result
// broadcast from lane 63 as an SGPR. (validated R9)
__device__ __forceinline__ float wave_fmin_bcast(float x) {
    float y;
#define DPPSTEP(ctrl) \
    y = __uint_as_float((unsigned)__builtin_amdgcn_update_dpp( \
            (int)__float_as_uint(x), (int)__float_as_uint(x), ctrl, 0xf, 0xf, false)); \
    x = fminf(x, y);
    DPPSTEP(0x111) DPPSTEP(0x112) DPPSTEP(0x114) DPPSTEP(0x118)
    DPPSTEP(0x142) DPPSTEP(0x143)
#undef DPPSTEP
    return rdlane_f(x, 63);
}

// ---------------------------------------------------------------------------
// Fused kernel: per batch b (one 64-lane wave), build the cost matrix
// DIRECTLY in LDS (lse + CE + SmoothL1, arithmetic copied verbatim from the
// validated standalone kernels => bit-identical cost), then run the R9
// Hungarian loop (verbatim — best measured: 1370us, three rewrites lost).
// Removes: lse kernel, cost kernel, 20.5MB HBM cost write+read, 2 launches.
// Determinism: all global reads are of immutable inputs; LDS writes precede
// all main-loop reads within the single wave (DS ops in-order, no barrier).
// Lane t owns columns j = 1+t+64k (k=0..3; k=3 valid only for t<8).
// ---------------------------------------------------------------------------
__global__ __launch_bounds__(64) void hungarian_kernel(const float* __restrict__ pc,
                                                       const float* __restrict__ pb,
                                                       const int*   __restrict__ tc,
                                                       const float* __restrict__ tb,
                                                       float* __restrict__ out) {
    const int b = blockIdx.x;
    const int t = threadIdx.x;
    const int base = b * QQ;

    __shared__ __align__(16) float cm[CMPAD];
    __shared__ float lse_s[QQ];

    // ---- per-lane column preload: cls, tbb, mask for owned columns
    int    clsk[4];
    float4 tbbk[4];
    float  maskk[4];
#pragma unroll
    for (int k = 0; k < 4; ++k) {
        int j = t + 64 * k;
        if (j < QQ) {
            clsk[k]  = tc[base + j];
            tbbk[k]  = *(const float4*)(tb + (size_t)(base + j) * 4);
            maskk[k] = (clsk[k] != 0) ? 1.f : 0.f;
        } else {
            clsk[k] = 0; tbbk[k] = make_float4(0.f, 0.f, 0.f, 0.f); maskk[k] = 0.f;
        }
    }

    // ---- lse phase: lane-per-row, sequential in c (bit-exact vs lse_kernel)
#pragma unroll
    for (int k = 0; k < 4; ++k) {
        int r = t + 64 * k;
        if (r < QQ) {
            const float* row = pc + (size_t)(base + r) * CC;
            float m = -INFINITY;
            for (int c = 0; c < CC; ++c) m = fmaxf(m, row[c]);
            float s = 0.f;
            for (int c = 0; c < CC; ++c) s += expf(row[c] - m);
            lse_s[r] = m + logf(s);
        }
    }

    // ---- cost phase: row i, owned columns; same expression order as the
    //      validated cost_kernel => bit-identical cost matrix
    for (int i = 0; i < QQ; ++i) {
        const float  lsei  = lse_s[i];                 // uniform ds broadcast
        const float* pcrow = pc + (size_t)(base + i) * CC;
        const float4 pbb   = *(const float4*)(pb + (size_t)(base + i) * 4);
        float* cmrow = cm + i * QQ;
#pragma unroll
        for (int k = 0; k < 4; ++k) {
            if (k < 3 || t < 8) {                      // j = t+64k < 200
                float ce = lsei - pcrow[clsk[k]];
                float sl1 = 0.f;
                float d, ad;
                d = pbb.x - tbbk[k].x; ad = fabsf(d); sl1 += (ad < 1.f) ? 0.5f * d * d : (ad - 0.5f);
                d = pbb.y - tbbk[k].y; ad = fabsf(d); sl1 += (ad < 1.f) ? 0.5f * d * d : (ad - 0.5f);
                d = pbb.z - tbbk[k].z; ad = fabsf(d); sl1 += (ad < 1.f) ? 0.5f * d * d : (ad - 0.5f);
                d = pbb.w - tbbk[k].w; ad = fabsf(d); sl1 += (ad < 1.f) ? 0.5f * d * d : (ad - 0.5f);
                cmrow[t + 64 * k] = ce + sl1 * maskk[k];   // stride-1: conflict-free
            }
        }
    }

    // ======================= R9 Hungarian loop (verbatim) ===================
    const float INF = 1e9f;
    const int nval = (t < 8) ? 4 : 3;   // slot k valid iff 1+t+64k <= 200

    float v[4]     = {0.f, 0.f, 0.f, 0.f};
    int   pslot[4] = {0, 0, 0, 0};      // p for owned columns (0 = free)
    float uslot[4] = {0.f, 0.f, 0.f, 0.f};  // u of row matched to owned column
    float minv[4];
    int   waysl[4];
    int   usedm;
    float usent;

    for (int i = 1; i <= QQ; ++i) {
        minv[0] = minv[1] = minv[2] = minv[3] = INF;
        waysl[0] = waysl[1] = waysl[2] = waysl[3] = 0;
        usedm = 0;
        usent = 0.f;                    // u[i] == 0 at phase start
        int j0 = 0;
        float u0 = 0.f;                 // u[i0] for current iteration
        const float* crow = cm + (i - 1) * QQ;
        float c0 = crow[t];
        float c1 = crow[64 + t];
        float c2 = crow[128 + t];
        float c3 = crow[192 + t];       // pad keeps this in-bounds

        for (;;) {
            // ---- mark j0 used (owner lane)
            if (j0 > 0) {
                int s = (j0 - 1) >> 6;
                if (((j0 - 1) & 63) == t) usedm |= 1 << s;
            }

            // ---- scan owned columns (gated on !used: way entries freeze)
            float kv0, kv1, kv2, kv3;
            {
                float cur;
                cur = c0 - u0 - v[0];
                if (!(usedm & 1) && cur < minv[0]) { minv[0] = cur; waysl[0] = j0; }
                kv0 = (usedm & 1) ? INF : minv[0];
                cur = c1 - u0 - v[1];
                if (!(usedm & 2) && cur < minv[1]) { minv[1] = cur; waysl[1] = j0; }
                kv1 = (usedm & 2) ? INF : minv[1];
                cur = c2 - u0 - v[2];
                if (!(usedm & 4) && cur < minv[2]) { minv[2] = cur; waysl[2] = j0; }
                kv2 = (usedm & 4) ? INF : minv[2];
                cur = c3 - u0 - v[3];
                if (!(usedm & 8) && t < 8 && cur < minv[3]) { minv[3] = cur; waysl[3] = j0; }
                kv3 = ((usedm & 8) || t >= 8) ? INF : minv[3];
            }

            float gmin = wave_fmin_bcast(fminf(fminf(kv0, kv1), fminf(kv2, kv3)));
            float delta = gmin;

            // ---- smallest j with kv==gmin: k-major, lowest lane
            unsigned long long m0 = __ballot(kv0 == gmin);
            unsigned long long m1 = __ballot(kv1 == gmin);
            unsigned long long m2 = __ballot(kv2 == gmin);
            unsigned long long m3 = __ballot(kv3 == gmin);
            int j1;
            if (m0)      j1 = 1   + (int)__builtin_ctzll(m0);
            else if (m1) j1 = 65  + (int)__builtin_ctzll(m1);
            else if (m2) j1 = 129 + (int)__builtin_ctzll(m2);
            else         j1 = 193 + (int)__builtin_ctzll(m3);

            // ---- matched row + its dual from j1's owner lane (j1 uniform)
            int kk = (j1 - 1) >> 6, ln = (j1 - 1) & 63;
            int   ps = (kk == 0) ? pslot[0] : (kk == 1) ? pslot[1]
                      : (kk == 2) ? pslot[2] : pslot[3];
            float us = (kk == 0) ? uslot[0] : (kk == 1) ? uslot[1]
                      : (kk == 2) ? uslot[2] : uslot[3];
            int pi = rdlane_i(ps, ln);

            // ---- issue next row's reads NOW (cm immutable: no hazard);
            //      ~120cyc latency overlaps updates + u0n readlane below
            int nr = (pi > 0 ? pi : 1) - 1;
            const float* nrow = cm + nr * QQ;
            float n0 = nrow[t];
            float n1 = nrow[64 + t];
            float n2 = nrow[128 + t];
            float n3 = nrow[192 + t];

            float u0n = rdlane_f(us, ln);

            // ---- updates (identical fp-op sequence to reference)
#pragma unroll
            for (int k = 0; k < 4; ++k) {
                if (usedm & (1 << k)) {
                    v[k] -= delta;
                    uslot[k] += delta;               // == u[p[j]] += delta
                } else if (k < nval) {
                    minv[k] -= delta;
                }
            }
            usent += delta;                          // == u[i] += delta (sentinel)

            if (pi == 0) { j0 = j1; break; }
            j0 = j1; u0 = u0n;
            c0 = n0; c1 = n1; c2 = n2; c3 = n3;
        }

        // ---- augment: flip matching along alternating path (uniform walk;
        //      way/p/u served from registers via readlane; entries frozen)
        {
            int jj = j0;
            while (jj != 0) {
                int jm = jj - 1, km = jm >> 6, lm = jm & 63;
                int ws = (km == 0) ? waysl[0] : (km == 1) ? waysl[1]
                        : (km == 2) ? waysl[2] : waysl[3];
                int jn = rdlane_i(ws, lm);
                int pnew; float unew;
                if (jn == 0) {
                    pnew = i;                        // p[0] = i (sentinel)
                    unew = usent;                    // u[i] accumulated this phase
                } else {
                    int jm2 = jn - 1, kn = jm2 >> 6, ln2 = jm2 & 63;
                    int   ps2 = (kn == 0) ? pslot[0] : (kn == 1) ? pslot[1]
                               : (kn == 2) ? pslot[2] : pslot[3];
                    float us2 = (kn == 0) ? uslot[0] : (kn == 1) ? uslot[1]
                               : (kn == 2) ? uslot[2] : uslot[3];
                    pnew = rdlane_i(ps2, ln2);
                    unew = rdlane_f(us2, ln2);
                }
                if (lm == t) { pslot[km] = pnew; uslot[km] = unew; }
                jj = jn;
            }
        }
    }

    // pslot[k] = row matched to owned column jc; emit per-row matched cost
#pragma unroll
    for (int k = 0; k < 4; ++k) {
        if (k < nval) {
            int jc = 1 + t + 64 * k;
            int row = pslot[k] - 1;
            out[b * QQ + row] = cm[row * QQ + (jc - 1)];
        }
    }
}

// ---------------------------------------------------------------------------
extern "C" void kernel_launch(void* const* d_in, const int* in_sizes, int n_in,
                              void* d_out, int out_size, void* d_ws, size_t ws_size,
                              hipStream_t stream) {
    const float* pred_cat  = (const float*)d_in[0];
    const float* pred_bbox = (const float*)d_in[1];
    const int*   tar_cat   = (const int*)d_in[2];
    const float* tar_bbox  = (const float*)d_in[3];
    float* out = (float*)d_out;
    (void)d_ws; (void)ws_size;   // cost matrix now built directly in LDS

    hungarian_kernel<<<BB, 64, 0, stream>>>(pred_cat, pred_bbox, tar_cat,
                                            tar_bbox, out);
}

// Round 14
// 1486.065 us; speedup vs baseline: 1.2376x; 1.0110x over previous
//
#include <hip/hip_runtime.h>
#include <math.h>

#define BB 128
#define QQ 200
#define CC 92
#define CMPAD (QQ * QQ + 64) // pad so c3 = crow[192+t] stays in-bounds for t<64

// ---------------------------------------------------------------------------
__device__ __forceinline__ int rdlane_i(int x, int l) { return __builtin_amdgcn_readlane(x, l); }
__device__ __forceinline__ float rdlane_f(float x, int l) {
    return __uint_as_float((unsigned)__builtin_amdgcn_readlane((int)__float_as_uint(x), l));
}

// wave64 float min-reduce via DPP (row_shr 1/2/4/8, row_bcast 15/31), result
// broadcast from lane 63 as an SGPR. (validated R9)
__device__ __forceinline__ float wave_fmin_bcast(float x) {
    float y;
#define DPPSTEP(ctrl) \
    y = __uint_as_float((unsigned)__builtin_amdgcn_update_dpp( \
            (int)__float_as_uint(x), (int)__float_as_uint(x), ctrl, 0xf, 0xf, false)); \
    x = fminf(x, y);
    DPPSTEP(0x111) DPPSTEP(0x112) DPPSTEP(0x114) DPPSTEP(0x118)
    DPPSTEP(0x142) DPPSTEP(0x143)
#undef DPPSTEP
    return rdlane_f(x, 63);
}

// ---------------------------------------------------------------------------
// Fused kernel, 4 waves/block (R14): all 4 waves cooperatively build the
// cost matrix in LDS (lse: thread-per-row, one pass; cost: 50 rows per wave,
// arithmetic verbatim from the validated kernels => bit-identical cost).
// One __syncthreads, then waves 1-3 exit and wave 0 runs the R9 Hungarian
// loop verbatim (best measured; R10/R11/R12 rewrites all lost to it).
// Determinism: global reads of immutable inputs; LDS read-only after barrier.
// Wave-0 lane t owns columns j = 1+t+64k (k=0..3; k=3 valid only for t<8).
// ---------------------------------------------------------------------------
__global__ __launch_bounds__(256) void hungarian_kernel(const float* __restrict__ pc,
                                                        const float* __restrict__ pb,
                                                        const int*   __restrict__ tc,
                                                        const float* __restrict__ tb,
                                                        float* __restrict__ out) {
    const int b    = blockIdx.x;
    const int tid  = threadIdx.x;
    const int t    = tid & 63;           // lane within wave
    const int wid  = tid >> 6;           // wave id 0..3
    const int base = b * QQ;

    __shared__ __align__(16) float cm[CMPAD];
    __shared__ float lse_s[QQ];

    // ---- lse phase: thread-per-row, one pass (bit-exact vs lse_kernel)
    if (tid < QQ) {
        const float* row = pc + (size_t)(base + tid) * CC;
        float m = -INFINITY;
        for (int c = 0; c < CC; ++c) m = fmaxf(m, row[c]);
        float s = 0.f;
        for (int c = 0; c < CC; ++c) s += expf(row[c] - m);
        lse_s[tid] = m + logf(s);
    }

    // ---- per-lane column preload (each wave loads its own copy; L1-hot)
    int    clsk[4];
    float4 tbbk[4];
    float  maskk[4];
#pragma unroll
    for (int k = 0; k < 4; ++k) {
        int j = t + 64 * k;
        if (j < QQ) {
            clsk[k]  = tc[base + j];
            tbbk[k]  = *(const float4*)(tb + (size_t)(base + j) * 4);
            maskk[k] = (clsk[k] != 0) ? 1.f : 0.f;
        } else {
            clsk[k] = 0; tbbk[k] = make_float4(0.f, 0.f, 0.f, 0.f); maskk[k] = 0.f;
        }
    }
    __syncthreads();   // lse_s ready (cost phase below reads it)

    // ---- cost phase: wave w handles rows 50w..50w+49 (disjoint writes);
    //      same expression order as validated cost_kernel => identical bits
    for (int i = wid * 50; i < wid * 50 + 50; ++i) {
        const float  lsei  = lse_s[i];
        const float* pcrow = pc + (size_t)(base + i) * CC;
        const float4 pbb   = *(const float4*)(pb + (size_t)(base + i) * 4);
        float* cmrow = cm + i * QQ;
#pragma unroll
        for (int k = 0; k < 4; ++k) {
            if (k < 3 || t < 8) {                      // j = t+64k < 200
                float ce = lsei - pcrow[clsk[k]];
                float sl1 = 0.f;
                float d, ad;
                d = pbb.x - tbbk[k].x; ad = fabsf(d); sl1 += (ad < 1.f) ? 0.5f * d * d : (ad - 0.5f);
                d = pbb.y - tbbk[k].y; ad = fabsf(d); sl1 += (ad < 1.f) ? 0.5f * d * d : (ad - 0.5f);
                d = pbb.z - tbbk[k].z; ad = fabsf(d); sl1 += (ad < 1.f) ? 0.5f * d * d : (ad - 0.5f);
                d = pbb.w - tbbk[k].w; ad = fabsf(d); sl1 += (ad < 1.f) ? 0.5f * d * d : (ad - 0.5f);
                cmrow[t + 64 * k] = ce + sl1 * maskk[k];   // stride-1: conflict-free
            }
        }
    }
    __syncthreads();   // cm ready
    if (wid != 0) return;   // staging waves done; wave 0 runs the solver

    // ======================= R9 Hungarian loop (verbatim) ===================
    const float INF = 1e9f;
    const int nval = (t < 8) ? 4 : 3;   // slot k valid iff 1+t+64k <= 200

    float v[4]     = {0.f, 0.f, 0.f, 0.f};
    int   pslot[4] = {0, 0, 0, 0};      // p for owned columns (0 = free)
    float uslot[4] = {0.f, 0.f, 0.f, 0.f};  // u of row matched to owned column
    float minv[4];
    int   waysl[4];
    int   usedm;
    float usent;

    for (int i = 1; i <= QQ; ++i) {
        minv[0] = minv[1] = minv[2] = minv[3] = INF;
        waysl[0] = waysl[1] = waysl[2] = waysl[3] = 0;
        usedm = 0;
        usent = 0.f;                    // u[i] == 0 at phase start
        int j0 = 0;
        float u0 = 0.f;                 // u[i0] for current iteration
        const float* crow = cm + (i - 1) * QQ;
        float c0 = crow[t];
        float c1 = crow[64 + t];
        float c2 = crow[128 + t];
        float c3 = crow[192 + t];       // pad keeps this in-bounds

        for (;;) {
            // ---- mark j0 used (owner lane)
            if (j0 > 0) {
                int s = (j0 - 1) >> 6;
                if (((j0 - 1) & 63) == t) usedm |= 1 << s;
            }

            // ---- scan owned columns (gated on !used: way entries freeze)
            float kv0, kv1, kv2, kv3;
            {
                float cur;
                cur = c0 - u0 - v[0];
                if (!(usedm & 1) && cur < minv[0]) { minv[0] = cur; waysl[0] = j0; }
                kv0 = (usedm & 1) ? INF : minv[0];
                cur = c1 - u0 - v[1];
                if (!(usedm & 2) && cur < minv[1]) { minv[1] = cur; waysl[1] = j0; }
                kv1 = (usedm & 2) ? INF : minv[1];
                cur = c2 - u0 - v[2];
                if (!(usedm & 4) && cur < minv[2]) { minv[2] = cur; waysl[2] = j0; }
                kv2 = (usedm & 4) ? INF : minv[2];
                cur = c3 - u0 - v[3];
                if (!(usedm & 8) && t < 8 && cur < minv[3]) { minv[3] = cur; waysl[3] = j0; }
                kv3 = ((usedm & 8) || t >= 8) ? INF : minv[3];
            }

            float gmin = wave_fmin_bcast(fminf(fminf(kv0, kv1), fminf(kv2, kv3)));
            float delta = gmin;

            // ---- smallest j with kv==gmin: k-major, lowest lane
            unsigned long long m0 = __ballot(kv0 == gmin);
            unsigned long long m1 = __ballot(kv1 == gmin);
            unsigned long long m2 = __ballot(kv2 == gmin);
            unsigned long long m3 = __ballot(kv3 == gmin);
            int j1;
            if (m0)      j1 = 1   + (int)__builtin_ctzll(m0);
            else if (m1) j1 = 65  + (int)__builtin_ctzll(m1);
            else if (m2) j1 = 129 + (int)__builtin_ctzll(m2);
            else         j1 = 193 + (int)__builtin_ctzll(m3);

            // ---- matched row + its dual from j1's owner lane (j1 uniform)
            int kk = (j1 - 1) >> 6, ln = (j1 - 1) & 63;
            int   ps = (kk == 0) ? pslot[0] : (kk == 1) ? pslot[1]
                      : (kk == 2) ? pslot[2] : pslot[3];
            float us = (kk == 0) ? uslot[0] : (kk == 1) ? uslot[1]
                      : (kk == 2) ? uslot[2] : uslot[3];
            int pi = rdlane_i(ps, ln);

            // ---- issue next row's reads NOW (cm immutable: no hazard);
            //      ~120cyc latency overlaps updates + u0n readlane below
            int nr = (pi > 0 ? pi : 1) - 1;
            const float* nrow = cm + nr * QQ;
            float n0 = nrow[t];
            float n1 = nrow[64 + t];
            float n2 = nrow[128 + t];
            float n3 = nrow[192 + t];

            float u0n = rdlane_f(us, ln);

            // ---- updates (identical fp-op sequence to reference)
#pragma unroll
            for (int k = 0; k < 4; ++k) {
                if (usedm & (1 << k)) {
                    v[k] -= delta;
                    uslot[k] += delta;               // == u[p[j]] += delta
                } else if (k < nval) {
                    minv[k] -= delta;
                }
            }
            usent += delta;                          // == u[i] += delta (sentinel)

            if (pi == 0) { j0 = j1; break; }
            j0 = j1; u0 = u0n;
            c0 = n0; c1 = n1; c2 = n2; c3 = n3;
        }

        // ---- augment: flip matching along alternating path (uniform walk;
        //      way/p/u served from registers via readlane; entries frozen)
        {
            int jj = j0;
            while (jj != 0) {
                int jm = jj - 1, km = jm >> 6, lm = jm & 63;
                int ws = (km == 0) ? waysl[0] : (km == 1) ? waysl[1]
                        : (km == 2) ? waysl[2] : waysl[3];
                int jn = rdlane_i(ws, lm);
                int pnew; float unew;
                if (jn == 0) {
                    pnew = i;                        // p[0] = i (sentinel)
                    unew = usent;                    // u[i] accumulated this phase
                } else {
                    int jm2 = jn - 1, kn = jm2 >> 6, ln2 = jm2 & 63;
                    int   ps2 = (kn == 0) ? pslot[0] : (kn == 1) ? pslot[1]
                               : (kn == 2) ? pslot[2] : pslot[3];
                    float us2 = (kn == 0) ? uslot[0] : (kn == 1) ? uslot[1]
                               : (kn == 2) ? uslot[2] : uslot[3];
                    pnew = rdlane_i(ps2, ln2);
                    unew = rdlane_f(us2, ln2);
                }
                if (lm == t) { pslot[km] = pnew; uslot[km] = unew; }
                jj = jn;
            }
        }
    }

    // pslot[k] = row matched to owned column jc; emit per-row matched cost
#pragma unroll
    for (int k = 0; k < 4; ++k) {
        if (k < nval) {
            int jc = 1 + t + 64 * k;
            int row = pslot[k] - 1;
            out[b * QQ + row] = cm[row * QQ + (jc - 1)];
        }
    }
}

// ---------------------------------------------------------------------------
extern "C" void kernel_launch(void* const* d_in, const int* in_sizes, int n_in,
                              void* d_out, int out_size, void* d_ws, size_t ws_size,
                              hipStream_t stream) {
    const float* pred_cat  = (const float*)d_in[0];
    const float* pred_bbox = (const float*)d_in[1];
    const int*   tar_cat   = (const int*)d_in[2];
    const float* tar_bbox  = (const float*)d_in[3];
    float* out = (float*)d_out;
    (void)d_ws; (void)ws_size;   // cost matrix built directly in LDS

    hungarian_kernel<<<BB, 256, 0, stream>>>(pred_cat, pred_bbox, tar_cat,
                                             tar_bbox, out);
}